// Round 8
// baseline (203.706 us; speedup 1.0000x reference)
//
#include <hip/hip_runtime.h>

// uDTW forward DP, R7: K=32 bursts (39 phases vs 71) + register double-buffer
// D prefetch. R6 post-mortem: ~4k cyc/phase of stall on top of 1.6k issue;
// the stalls are per-PHASE (phase-head vmcnt on the D quads, barrier, lgkm),
// so halve the phase count and hoist the D loads one full phase ahead into
// named registers (rotated in after the body; loads can't sink across
// __syncthreads). Funnel/publish/cell math identical to R6 (absmax 0.0).

constexpr int N = 512;
constexpr int M = 512;
constexpr int BATCH = 32;
constexpr int NM = N + M;                  // 1024; diags d = 2..NM
constexpr int K = 32;                      // diagonals per burst
constexpr int NB = 32;                     // bursts cover d = 2..1025
constexpr int PHASES = NB + 7;             // 39
constexpr float NL2E = -1.4426950408889634f;   // -log2(e)
constexpr float NLN2 = -0.6931471805599453f;   // -ln(2)

__device__ __forceinline__ float lane_shr1(float x) {
  // lane n gets lane n-1's x; lane 0 gets 0 (overridden by caller).
  return __int_as_float(
      __builtin_amdgcn_update_dpp(0, __float_as_int(x), 0x138, 0xf, 0xf, true));
}

__device__ __forceinline__ int qclamp(int q) {
  return q < 0 ? 0 : (q > 127 ? 127 : q);
}

__global__ __launch_bounds__(512, 2)
void softdtw_fwd(const float* __restrict__ D,
                 const float* __restrict__ Sig,
                 float* __restrict__ out) {
  const int b = blockIdx.x;
  const int t = threadIdx.x;           // row r = t, cell i = t+1
  const int w = t >> 6;                // wave 0..7
  const bool l0 = ((t & 63) == 0);
  const float4* Drow4 = (const float4*)(D + ((size_t)b * N + t) * M);

  // edge[w][64 + c] = (exp(-R), NL2E*Ddiag) of row 64w+63 at column c.
  // c in [-64, 576): halos are never read as live data and stay (0,0).
  __shared__ float2 edge[8][640];
  for (int idx = t; idx < 8 * 640; idx += 512)
    ((float2*)edge)[idx] = make_float2(0.f, 0.f);

  // carried state: own cell at d-1, neighbor (i-1) at d-2 (D pre-scaled)
  float eSelf = 0.f, dSelfL = 0.f;
  float eN2 = (t == 0) ? 1.f : 0.f, dN2L = 0.f;   // R[0,0]=0 -> e=1

  // Sig contributes only via 4 elements at the final cell
  float sgA = 0.f, sg0 = 0.f, sg1 = 0.f, sg2 = 0.f;
  if (t == N - 1) {
    const float* Sb = Sig + (size_t)b * N * M;
    sgA = Sb[(size_t)(N - 1) * M + (M - 1)];
    sg0 = Sb[(size_t)(N - 2) * M + (M - 2)];
    sg1 = Sb[(size_t)(N - 2) * M + (M - 1)];
    sg2 = Sb[(size_t)(N - 1) * M + (M - 2)];
  }

  // burst B covers diags [2+32B, 33+32B]; wave w active for B in [2w, 2w+17]
  const int Bl = 2 * w, Bh = 2 * w + 17;

  // current-burst D window: 9 quads covering floats [4*((32B-t)>>2), +36)
  float4 r0, r1, r2, r3, r4, r5, r6, r7, r8;
  {
    const int q = (32 * Bl - t) >> 2;       // preload for first active burst
    r0 = Drow4[qclamp(q + 0)]; r1 = Drow4[qclamp(q + 1)];
    r2 = Drow4[qclamp(q + 2)]; r3 = Drow4[qclamp(q + 3)];
    r4 = Drow4[qclamp(q + 4)]; r5 = Drow4[qclamp(q + 5)];
    r6 = Drow4[qclamp(q + 6)]; r7 = Drow4[qclamp(q + 7)];
    r8 = Drow4[qclamp(q + 8)];
  }
  __syncthreads();

  for (int p = 0; p < PHASES; ++p) {
    const int B = p - w;
    const int nB = B + 1;
    const bool dopre = (nB >= Bl) && (nB <= Bh);   // wave-uniform

    // ---- prefetch next burst's D quads (consumed after the barrier)
    float4 p0, p1, p2, p3, p4, p5, p6, p7, p8;
    if (dopre) {
      const int q = (32 * nB - t) >> 2;
      p0 = Drow4[qclamp(q + 0)]; p1 = Drow4[qclamp(q + 1)];
      p2 = Drow4[qclamp(q + 2)]; p3 = Drow4[qclamp(q + 3)];
      p4 = Drow4[qclamp(q + 4)]; p5 = Drow4[qclamp(q + 5)];
      p6 = Drow4[qclamp(q + 6)]; p7 = Drow4[qclamp(q + 7)];
      p8 = Drow4[qclamp(q + 8)];
    }

    if (B >= Bl && B <= Bh) {
      const int d0 = 2 + B * K;
      const int c0 = d0 - t - 2;       // = 32B - t; in [-63, 544]

      // ---- neighbor boundary preload: 16 float4 (32 (E,D) pairs).
      // producer (row 64w-1) col for my diag d is cp = d - 64w - 2.
      float4 n0, n1, n2, n3, n4, n5, n6, n7, n8, n9, n10, n11, n12, n13, n14, n15;
      if (w > 0) {
        const float4* ep = (const float4*)&edge[w - 1][64 + (d0 - 64 * w - 2)];
        n0 = ep[0];  n1 = ep[1];  n2 = ep[2];  n3 = ep[3];
        n4 = ep[4];  n5 = ep[5];  n6 = ep[6];  n7 = ep[7];
        n8 = ep[8];  n9 = ep[9];  n10 = ep[10]; n11 = ep[11];
        n12 = ep[12]; n13 = ep[13]; n14 = ep[14]; n15 = ep[15];
      } else {
        const float4 z = make_float4(0.f, 0.f, 0.f, 0.f);
        n0 = n1 = n2 = n3 = n4 = n5 = n6 = n7 = z;
        n8 = n9 = n10 = n11 = n12 = n13 = n14 = n15 = z;
      }

      // ---- funnel align by s = c0 & 3: g_e = D[c0 + e], e in [0,32)
      const int s = c0 & 3;
      const bool s2 = (s & 2) != 0, s1b = (s & 1) != 0;
      const float
        f0 = r0.x, f1 = r0.y, f2 = r0.z, f3 = r0.w,
        f4 = r1.x, f5 = r1.y, f6 = r1.z, f7 = r1.w,
        f8 = r2.x, f9 = r2.y, f10 = r2.z, f11 = r2.w,
        f12 = r3.x, f13 = r3.y, f14 = r3.z, f15 = r3.w,
        f16 = r4.x, f17 = r4.y, f18 = r4.z, f19 = r4.w,
        f20 = r5.x, f21 = r5.y, f22 = r5.z, f23 = r5.w,
        f24 = r6.x, f25 = r6.y, f26 = r6.z, f27 = r6.w,
        f28 = r7.x, f29 = r7.y, f30 = r7.z, f31 = r7.w,
        f32 = r8.x, f33 = r8.y, f34 = r8.z, f35 = r8.w;
      const float
        x0  = s2 ? f2  : f0,  x1  = s2 ? f3  : f1,  x2  = s2 ? f4  : f2,
        x3  = s2 ? f5  : f3,  x4  = s2 ? f6  : f4,  x5  = s2 ? f7  : f5,
        x6  = s2 ? f8  : f6,  x7  = s2 ? f9  : f7,  x8  = s2 ? f10 : f8,
        x9  = s2 ? f11 : f9,  x10 = s2 ? f12 : f10, x11 = s2 ? f13 : f11,
        x12 = s2 ? f14 : f12, x13 = s2 ? f15 : f13, x14 = s2 ? f16 : f14,
        x15 = s2 ? f17 : f15, x16 = s2 ? f18 : f16, x17 = s2 ? f19 : f17,
        x18 = s2 ? f20 : f18, x19 = s2 ? f21 : f19, x20 = s2 ? f22 : f20,
        x21 = s2 ? f23 : f21, x22 = s2 ? f24 : f22, x23 = s2 ? f25 : f23,
        x24 = s2 ? f26 : f24, x25 = s2 ? f27 : f25, x26 = s2 ? f28 : f26,
        x27 = s2 ? f29 : f27, x28 = s2 ? f30 : f28, x29 = s2 ? f31 : f29,
        x30 = s2 ? f32 : f30, x31 = s2 ? f33 : f31, x32 = s2 ? f34 : f32;
      const float
        g0  = s1b ? x1  : x0,  g1  = s1b ? x2  : x1,  g2  = s1b ? x3  : x2,
        g3  = s1b ? x4  : x3,  g4  = s1b ? x5  : x4,  g5  = s1b ? x6  : x5,
        g6  = s1b ? x7  : x6,  g7  = s1b ? x8  : x7,  g8  = s1b ? x9  : x8,
        g9  = s1b ? x10 : x9,  g10 = s1b ? x11 : x10, g11 = s1b ? x12 : x11,
        g12 = s1b ? x13 : x12, g13 = s1b ? x14 : x13, g14 = s1b ? x15 : x14,
        g15 = s1b ? x16 : x15, g16 = s1b ? x17 : x16, g17 = s1b ? x18 : x17,
        g18 = s1b ? x19 : x18, g19 = s1b ? x20 : x19, g20 = s1b ? x21 : x20,
        g21 = s1b ? x22 : x21, g22 = s1b ? x23 : x22, g23 = s1b ? x24 : x23,
        g24 = s1b ? x25 : x24, g25 = s1b ? x26 : x25, g26 = s1b ? x27 : x26,
        g27 = s1b ? x28 : x27, g28 = s1b ? x29 : x28, g29 = s1b ? x30 : x29,
        g30 = s1b ? x31 : x30, g31 = s1b ? x32 : x31;

      float2* eput = &edge[w][64 + c0];   // my publish slots (write-once)

#define STEP(kk, GK, NE, ND)                                                   \
      {                                                                        \
        const int d = d0 + (kk);                                               \
        const int c = c0 + (kk);                                               \
        const bool valid = ((unsigned)c) < 512u;                               \
        float ddL = (GK) * NL2E;                                               \
        ddL = valid ? ddL : 0.f;                                               \
        float sE = lane_shr1(eSelf);                                           \
        float sD = lane_shr1(dSelfL);                                          \
        sE = l0 ? (NE) : sE;                                                   \
        sD = l0 ? (ND) : sD;                                                   \
        const float e0 = eN2, e1 = sE, e2 = eSelf;                             \
        const float sum = (e0 + e2) + e1;                                      \
        const float inv = __builtin_amdgcn_rcpf(sum);                          \
        const float numL = fmaf(e0, dN2L, fmaf(e1, sD, e2 * dSelfL));          \
        const float rr = fmaf(inv, numL, ddL);                                 \
        float newE = __builtin_amdgcn_exp2f(rr);                               \
        newE = valid ? newE : 0.f;                                             \
        if (d == NM && t == N - 1) {                                           \
          out[b] = rr * NLN2;                                                  \
          out[BATCH + b] = sgA + inv * (e0 * sg0 + e1 * sg1 + e2 * sg2);       \
        }                                                                      \
        eN2 = e1; dN2L = sD;                                                   \
        eSelf = newE; dSelfL = ddL;                                            \
        eput[kk] = make_float2(newE, ddL);                                     \
      }
#define STEP2(m, GA, GB)                                                       \
      STEP(2 * m, GA, n##m.x, n##m.y)                                          \
      STEP(2 * m + 1, GB, n##m.z, n##m.w)

      STEP2(0,  g0,  g1)   STEP2(1,  g2,  g3)
      STEP2(2,  g4,  g5)   STEP2(3,  g6,  g7)
      STEP2(4,  g8,  g9)   STEP2(5,  g10, g11)
      STEP2(6,  g12, g13)  STEP2(7,  g14, g15)
      STEP2(8,  g16, g17)  STEP2(9,  g18, g19)
      STEP2(10, g20, g21)  STEP2(11, g22, g23)
      STEP2(12, g24, g25)  STEP2(13, g26, g27)
      STEP2(14, g28, g29)  STEP2(15, g30, g31)
#undef STEP2
#undef STEP
    }

    // rotate in the prefetched window (waitcnt lands here, ~600 inst later)
    if (dopre) {
      r0 = p0; r1 = p1; r2 = p2; r3 = p3; r4 = p4;
      r5 = p5; r6 = p6; r7 = p7; r8 = p8;
    }
    __syncthreads();
  }
}

extern "C" void kernel_launch(void* const* d_in, const int* in_sizes, int n_in,
                              void* d_out, int out_size, void* d_ws, size_t ws_size,
                              hipStream_t stream) {
  const float* D   = (const float*)d_in[0];
  const float* Sig = (const float*)d_in[1];
  float* out = (float*)d_out;
  softdtw_fwd<<<dim3(BATCH), dim3(512), 0, stream>>>(D, Sig, out);
}